// Round 2
// baseline (4560.142 us; speedup 1.0000x reference)
//
#include <hip/hip_runtime.h>
#include <float.h>

constexpr int cB = 8;
constexpr int cN = 2048;
constexpr int cKnn = 20;
constexpr float F_EPS = 1e-5f;
constexpr float F_SLOPE = 0.2f;

__device__ __forceinline__ float lrelu(float x){ return x >= 0.f ? x : F_SLOPE * x; }

// ---------------- transpose x (B,3,N) -> xt (B,N,3) ----------------
__global__ void k_transpose3(const float* __restrict__ x, float* __restrict__ xt){
    int i = blockIdx.x * 256 + threadIdx.x;
    if(i >= cB * cN) return;
    int b = i / cN, n = i % cN;
    const float* xb = x + (size_t)b * 3 * cN;
    float* o = xt + (size_t)i * 3;
    o[0] = xb[n]; o[1] = xb[cN + n]; o[2] = xb[2*cN + n];
}

// ---------------- xx[b][n] = sum_c xt[b][n][c]^2 ----------------
template<int C>
__global__ void k_xx(const float* __restrict__ xt, float* __restrict__ xx){
    int i = blockIdx.x * 256 + threadIdx.x;
    if(i >= cB * cN) return;
    const float* r = xt + (size_t)i * C;
    float s = 0.f;
    if constexpr (C == 3){
        s = r[0]*r[0] + r[1]*r[1] + r[2]*r[2];
    } else {
        const float4* r4 = (const float4*)r;
        #pragma unroll
        for(int c = 0; c < C/4; c++){
            float4 v = r4[c];
            s += v.x*v.x + v.y*v.y + v.z*v.z + v.w*v.w;
        }
    }
    xx[i] = s;
}

// ---------------- knn top-20 ----------------
// score = 2*dot(q, xj) - xx[j]  (row-constant -xx_i dropped; same ordering as ref pd)
template<int C>
__global__ __launch_bounds__(256) void k_knn(const float* __restrict__ xt,
                                             const float* __restrict__ xx,
                                             int* __restrict__ idxout){
    constexpr int QB = 32;        // queries per block
    constexpr int SPL = 8;        // j-splits per query
    constexpr int TJ = 64;        // j tile
    constexpr int C4 = (C == 3) ? 1 : (C/4);
    constexpr int JROW = C4 + 1;  // float4 units, padded
    constexpr int MSTR = SPL * cKnn + 1;  // per-query merge stride (floats), +1 de-banks
    constexpr int SMF = (TJ*JROW*4 > 2*QB*MSTR) ? TJ*JROW*4 : 2*QB*MSTR;

    __shared__ __align__(16) float4 sm4[(SMF + 3) / 4];
    __shared__ float xxt[TJ];
    float4* jt = sm4;
    float* mv = (float*)sm4;
    int*   mi = (int*)((float*)sm4 + QB * MSTR);

    int tid = threadIdx.x;
    int q = tid >> 3;      // 0..31
    int r = tid & 7;       // 0..7
    int b = blockIdx.y;
    int n0 = blockIdx.x * QB;
    int n = n0 + q;

    float4 qv[C4];
    if constexpr (C == 3){
        const float* rw = xt + ((size_t)b * cN + n) * 3;
        qv[0] = make_float4(rw[0], rw[1], rw[2], 0.f);
    } else {
        const float4* r4 = (const float4*)(xt + ((size_t)b * cN + n) * C);
        #pragma unroll
        for(int c4 = 0; c4 < C4; c4++) qv[c4] = r4[c4];
    }

    float vals[cKnn];
    int   idxs[cKnn];
    #pragma unroll
    for(int k = 0; k < cKnn; k++){ vals[k] = -FLT_MAX; idxs[k] = 0; }

    for(int t0 = 0; t0 < cN; t0 += TJ){
        // stage tile
        if constexpr (C == 3){
            for(int e = tid; e < TJ; e += 256){
                const float* rw = xt + ((size_t)b * cN + t0 + e) * 3;
                jt[e * JROW] = make_float4(rw[0], rw[1], rw[2], 0.f);
            }
        } else {
            const float4* src = (const float4*)(xt + ((size_t)b * cN + t0) * C);
            for(int e = tid; e < TJ * C4; e += 256){
                jt[(e / C4) * JROW + (e % C4)] = src[e];
            }
        }
        for(int e = tid; e < TJ; e += 256) xxt[e] = xx[(size_t)b * cN + t0 + e];
        __syncthreads();

        #pragma unroll 2
        for(int s = 0; s < TJ / SPL; s++){
            int jj = s * SPL + r;
            const float4* row = jt + jj * JROW;
            float dot = 0.f;
            #pragma unroll
            for(int c4 = 0; c4 < C4; c4++){
                float4 a = qv[c4], bv = row[c4];
                dot += a.x*bv.x + a.y*bv.y + a.z*bv.z + a.w*bv.w;
            }
            float sc = 2.f * dot - xxt[jj];
            if(sc > vals[cKnn - 1]){
                float cv = sc; int ci = t0 + jj;
                bool started = false;
                #pragma unroll
                for(int kk = 0; kk < cKnn; kk++){
                    bool ins = started || (cv > vals[kk]);
                    float tv = vals[kk]; int ti = idxs[kk];
                    if(ins){ vals[kk] = cv; idxs[kk] = ci; cv = tv; ci = ti; started = true; }
                }
            }
        }
        __syncthreads();
    }

    // dump per-thread lists
    {
        float* mvq = mv + q * MSTR + r * cKnn;
        int*   miq = mi + q * MSTR + r * cKnn;
        #pragma unroll
        for(int kk = 0; kk < cKnn; kk++){ mvq[kk] = vals[kk]; miq[kk] = idxs[kk]; }
    }
    __syncthreads();

    // merge SPL sorted lists -> 20, tie-break: lower index first (matches lax.top_k)
    if(tid < QB){
        int qq = tid;
        int* out = idxout + ((size_t)b * cN + n0 + qq) * cKnn;
        int pr[SPL];
        #pragma unroll
        for(int r2 = 0; r2 < SPL; r2++) pr[r2] = 0;
        for(int k = 0; k < cKnn; k++){
            float bv = -FLT_MAX; int bi = 0x7fffffff; int br = 0;
            #pragma unroll
            for(int r2 = 0; r2 < SPL; r2++){
                float v = mv[qq * MSTR + r2 * cKnn + pr[r2]];
                int ii  = mi[qq * MSTR + r2 * cKnn + pr[r2]];
                bool better = (v > bv) || (v == bv && ii < bi);
                if(better){ bv = v; bi = ii; br = r2; }
            }
            out[k] = bi;
            #pragma unroll
            for(int r2 = 0; r2 < SPL; r2++) pr[r2] += (r2 == br) ? 1 : 0;
        }
    }
}

// ---------------- weight prep: w (O,2Cin) -> wt1[c][o]=w[o][c] (applied to nbr-ctr),
// ----------------                        wtd[c][o]=w[o][Cin+c] (applied to ctr) ----
template<int Cin, int O>
__global__ void k_prepw(const float* __restrict__ w, float* __restrict__ wt1, float* __restrict__ wtd){
    int e = blockIdx.x * 256 + threadIdx.x;
    if(e >= Cin * O) return;
    int o = e % O, c = e / O;
    float a = w[o * 2 * Cin + c];
    float d = w[o * 2 * Cin + Cin + c];
    wt1[c * O + o] = a;
    wtd[c * O + o] = d;   // FIX: y = w_lo*(nbr-ctr) + w_hi*ctr  (was w_hi - w_lo: wrong decomposition)
}

// ---------------- edge conv + max_k + stats ----------------
// y[o][k] = sum_c wt1[c][o]*(nbr_c - ctr_c) + sum_c wtd[c][o]*ctr_c
// Mbuf layout (B,N,O). Stats bucketed: bsum/bsq[64][O].
template<int Cin, int O>
__global__ __launch_bounds__(256) void k_conv(const float* __restrict__ xt, const int* __restrict__ idx,
                                              const float* __restrict__ wt1, const float* __restrict__ wtd,
                                              float* __restrict__ Mbuf, float* __restrict__ bsum, float* __restrict__ bsq){
    constexpr int P = 4;
    constexpr int GR = 256 / O;
    constexpr int PSER = P / GR;
    __shared__ float ctr[P][Cin];
    __shared__ __align__(16) float df[P][Cin][cKnn];

    int tid = threadIdx.x;
    int b = blockIdx.y;
    int n0 = blockIdx.x * P;
    const float* xb = xt + (size_t)b * cN * Cin;

    for(int e = tid; e < P * Cin; e += 256){
        int p = e / Cin, c = e % Cin;
        ctr[p][c] = xb[(size_t)(n0 + p) * Cin + c];
    }
    __syncthreads();

    if constexpr (Cin % 4 == 0){
        constexpr int C4 = Cin / 4;
        for(int e = tid; e < P * cKnn * C4; e += 256){
            int p = e / (cKnn * C4); int rem = e % (cKnn * C4);
            int k = rem / C4; int c4 = rem % C4;
            int j = idx[((size_t)b * cN + n0 + p) * cKnn + k];
            float4 v = *(const float4*)(xb + (size_t)j * Cin + c4 * 4);
            int c = c4 * 4;
            df[p][c  ][k] = v.x - ctr[p][c  ];
            df[p][c+1][k] = v.y - ctr[p][c+1];
            df[p][c+2][k] = v.z - ctr[p][c+2];
            df[p][c+3][k] = v.w - ctr[p][c+3];
        }
    } else {
        for(int e = tid; e < P * cKnn * Cin; e += 256){
            int p = e / (cKnn * Cin); int rem = e % (cKnn * Cin);
            int k = rem / Cin; int c = rem % Cin;
            int j = idx[((size_t)b * cN + n0 + p) * cKnn + k];
            df[p][c][k] = xb[(size_t)j * Cin + c] - ctr[p][c];
        }
    }
    __syncthreads();

    int o = tid % O;
    int grp = tid / O;
    float lsum = 0.f, lsq = 0.f;

    for(int s = 0; s < PSER; s++){
        int p = grp * PSER + s;
        float t = 0.f;
        for(int c = 0; c < Cin; c++) t += wtd[c * O + o] * ctr[p][c];
        float acc[cKnn];
        #pragma unroll
        for(int k = 0; k < cKnn; k++) acc[k] = t;
        for(int c = 0; c < Cin; c++){
            float wv = wt1[c * O + o];
            const float4* dr = (const float4*)&df[p][c][0];
            #pragma unroll
            for(int k4 = 0; k4 < cKnn / 4; k4++){
                float4 d4 = dr[k4];
                acc[k4*4+0] += wv * d4.x;
                acc[k4*4+1] += wv * d4.y;
                acc[k4*4+2] += wv * d4.z;
                acc[k4*4+3] += wv * d4.w;
            }
        }
        float mx = -FLT_MAX;
        #pragma unroll
        for(int k = 0; k < cKnn; k++){
            float y = acc[k];
            mx = fmaxf(mx, y);
            lsum += y; lsq += y * y;
        }
        Mbuf[((size_t)b * cN + n0 + p) * O + o] = mx;
    }
    int bkt = blockIdx.x & 63;
    atomicAdd(&bsum[bkt * O + o], lsum);
    atomicAdd(&bsq [bkt * O + o], lsq);
}

// ---------------- reduce buckets -> scale/shift ----------------
template<int O>
__global__ void k_redstats(const float* __restrict__ bsum, const float* __restrict__ bsq,
                           const float* __restrict__ g, const float* __restrict__ bb,
                           float2* __restrict__ stats, float invcnt){
    int o = threadIdx.x;
    if(o >= O) return;
    float s = 0.f, q = 0.f;
    for(int k = 0; k < 64; k++){ s += bsum[k * O + o]; q += bsq[k * O + o]; }
    float m = s * invcnt;
    float v = q * invcnt - m * m;
    float sc = g[o] * rsqrtf(v + F_EPS);
    stats[o] = make_float2(sc, bb[o] - m * sc);
}

// ---------------- normalize max-pooled values, write cat (+ xt for next layer) ----------------
template<int O, bool WXT>
__global__ void k_norm(const float* __restrict__ Mbuf, const float2* __restrict__ stats,
                       float* __restrict__ cat, float* __restrict__ xtn, int ooff){
    size_t i = (size_t)blockIdx.x * 256 + threadIdx.x;
    if(i >= (size_t)cB * cN * O) return;
    int o = i % O;
    size_t bn = i / O;
    int n = bn % cN; int b = bn / cN;
    float2 st = stats[o];
    float y = lrelu(Mbuf[i] * st.x + st.y);
    cat[((size_t)b * 512 + ooff + o) * cN + n] = y;
    if(WXT) xtn[i] = y;
}

// ---------------- z = w5 (1024,512) @ cat (B,512,N) -> (B,1024,N) ----------------
__global__ __launch_bounds__(256) void k_gemm_z(const float* __restrict__ w5, const float* __restrict__ cat,
                                                float* __restrict__ z){
    constexpr int CT = 16;
    __shared__ float at[CT][68];
    __shared__ float bt[CT][68];
    int tid = threadIdx.x;
    int n0 = blockIdx.x * 64, o0 = blockIdx.y * 64, b = blockIdx.z;
    int no = tid % 16, mo = tid / 16;
    float acc[4][4] = {};
    for(int c0 = 0; c0 < 512; c0 += CT){
        {
            int row = tid >> 2, c4 = tid & 3;
            float4 v = *(const float4*)(w5 + (size_t)(o0 + row) * 512 + c0 + c4 * 4);
            at[c4*4+0][row] = v.x; at[c4*4+1][row] = v.y;
            at[c4*4+2][row] = v.z; at[c4*4+3][row] = v.w;
        }
        {
            int cc = tid >> 4, n4 = tid & 15;
            float4 v = *(const float4*)(cat + ((size_t)b * 512 + c0 + cc) * cN + n0 + n4 * 4);
            bt[cc][n4*4+0] = v.x; bt[cc][n4*4+1] = v.y; bt[cc][n4*4+2] = v.z; bt[cc][n4*4+3] = v.w;
        }
        __syncthreads();
        #pragma unroll
        for(int c = 0; c < CT; c++){
            float av[4] = { at[c][mo*4+0], at[c][mo*4+1], at[c][mo*4+2], at[c][mo*4+3] };
            float bv[4] = { bt[c][no*4+0], bt[c][no*4+1], bt[c][no*4+2], bt[c][no*4+3] };
            #pragma unroll
            for(int i2 = 0; i2 < 4; i2++)
                #pragma unroll
                for(int j2 = 0; j2 < 4; j2++)
                    acc[i2][j2] += av[i2] * bv[j2];
        }
        __syncthreads();
    }
    #pragma unroll
    for(int i2 = 0; i2 < 4; i2++){
        float4 v = make_float4(acc[i2][0], acc[i2][1], acc[i2][2], acc[i2][3]);
        *(float4*)(z + ((size_t)b * 1024 + o0 + mo * 4 + i2) * cN + n0 + no * 4) = v;
    }
}

// ---------------- z stats per channel (over B,N) -> scale/shift ----------------
__global__ void k_zstats(const float* __restrict__ z, const float* __restrict__ g5,
                         const float* __restrict__ b5, float2* __restrict__ stats){
    int o = blockIdx.x;
    int tid = threadIdx.x;
    __shared__ float ss[256], sq[256];
    float s = 0.f, q = 0.f;
    for(int e = tid; e < cB * cN; e += 256){
        int b = e >> 11, n = e & 2047;
        float v = z[((size_t)b * 1024 + o) * cN + n];
        s += v; q += v * v;
    }
    ss[tid] = s; sq[tid] = q; __syncthreads();
    for(int st = 128; st; st >>= 1){
        if(tid < st){ ss[tid] += ss[tid + st]; sq[tid] += sq[tid + st]; }
        __syncthreads();
    }
    if(tid == 0){
        float m = ss[0] / (float)(cB * cN);
        float v = sq[0] / (float)(cB * cN) - m * m;
        float sc = g5[o] * rsqrtf(v + F_EPS);
        stats[o] = make_float2(sc, b5[o] - m * sc);
    }
}

// ---------------- pooling: p[b][o]=max_n y, p[b][1024+o]=mean_n y, y=lrelu(z*sc+sh) ----------------
__global__ void k_pool(const float* __restrict__ z, const float2* __restrict__ stats,
                       float* __restrict__ p){
    int o = blockIdx.x, b = blockIdx.y;
    int tid = threadIdx.x;
    float2 st = stats[o];
    const float* row = z + ((size_t)b * 1024 + o) * cN;
    float mx = -FLT_MAX, sm = 0.f;
    for(int n = tid; n < cN; n += 256){
        float y = lrelu(row[n] * st.x + st.y);
        mx = fmaxf(mx, y); sm += y;
    }
    __shared__ float smx[256], ssm[256];
    smx[tid] = mx; ssm[tid] = sm; __syncthreads();
    for(int st2 = 128; st2; st2 >>= 1){
        if(tid < st2){ smx[tid] = fmaxf(smx[tid], smx[tid + st2]); ssm[tid] += ssm[tid + st2]; }
        __syncthreads();
    }
    if(tid == 0){
        p[(size_t)b * 2048 + o] = smx[0];
        p[(size_t)b * 2048 + 1024 + o] = ssm[0] * (1.f / cN);
    }
}

// ---------------- FC layers with batch-axis BN ----------------
__global__ void k_fc1(const float* __restrict__ p, const float* __restrict__ lw1,
                      const float* __restrict__ g6, const float* __restrict__ b6,
                      float* __restrict__ h1){
    int f = blockIdx.x;        // 512
    int tid = threadIdx.x;     // 64
    const float* wrow = lw1 + (size_t)f * 2048;
    float acc[cB] = {};
    for(int i = tid; i < 2048; i += 64){
        float wv = wrow[i];
        #pragma unroll
        for(int b = 0; b < cB; b++) acc[b] += p[(size_t)b * 2048 + i] * wv;
    }
    #pragma unroll
    for(int b = 0; b < cB; b++){
        float v = acc[b];
        for(int off = 32; off; off >>= 1) v += __shfl_down(v, off);
        acc[b] = v;
    }
    if(tid == 0){
        float m = 0.f;
        #pragma unroll
        for(int b = 0; b < cB; b++) m += acc[b];
        m *= (1.f / cB);
        float var = 0.f;
        #pragma unroll
        for(int b = 0; b < cB; b++){ float d = acc[b] - m; var += d * d; }
        var *= (1.f / cB);
        float sc = g6[f] * rsqrtf(var + F_EPS);
        float sh = b6[f] - m * sc;
        #pragma unroll
        for(int b = 0; b < cB; b++) h1[(size_t)b * 512 + f] = lrelu(acc[b] * sc + sh);
    }
}

__global__ void k_fc2(const float* __restrict__ h1, const float* __restrict__ lw2,
                      const float* __restrict__ lb2, const float* __restrict__ g7,
                      const float* __restrict__ b7, float* __restrict__ h2){
    int f = blockIdx.x;        // 256
    int tid = threadIdx.x;     // 64
    const float* wrow = lw2 + (size_t)f * 512;
    float acc[cB] = {};
    for(int i = tid; i < 512; i += 64){
        float wv = wrow[i];
        #pragma unroll
        for(int b = 0; b < cB; b++) acc[b] += h1[(size_t)b * 512 + i] * wv;
    }
    #pragma unroll
    for(int b = 0; b < cB; b++){
        float v = acc[b];
        for(int off = 32; off; off >>= 1) v += __shfl_down(v, off);
        acc[b] = v;
    }
    if(tid == 0){
        float bias = lb2[f];
        #pragma unroll
        for(int b = 0; b < cB; b++) acc[b] += bias;
        float m = 0.f;
        #pragma unroll
        for(int b = 0; b < cB; b++) m += acc[b];
        m *= (1.f / cB);
        float var = 0.f;
        #pragma unroll
        for(int b = 0; b < cB; b++){ float d = acc[b] - m; var += d * d; }
        var *= (1.f / cB);
        float sc = g7[f] * rsqrtf(var + F_EPS);
        float sh = b7[f] - m * sc;
        #pragma unroll
        for(int b = 0; b < cB; b++) h2[(size_t)b * 256 + f] = lrelu(acc[b] * sc + sh);
    }
}

__global__ void k_fc3(const float* __restrict__ h2, const float* __restrict__ lw3,
                      const float* __restrict__ lb3, float* __restrict__ out){
    int cls = blockIdx.x;      // 40
    int tid = threadIdx.x;     // 64
    const float* wrow = lw3 + (size_t)cls * 256;
    float acc[cB] = {};
    for(int i = tid; i < 256; i += 64){
        float wv = wrow[i];
        #pragma unroll
        for(int b = 0; b < cB; b++) acc[b] += h2[(size_t)b * 256 + i] * wv;
    }
    #pragma unroll
    for(int b = 0; b < cB; b++){
        float v = acc[b];
        for(int off = 32; off; off >>= 1) v += __shfl_down(v, off);
        acc[b] = v;
    }
    if(tid == 0){
        float bias = lb3[cls];
        #pragma unroll
        for(int b = 0; b < cB; b++) out[(size_t)b * 40 + cls] = acc[b] + bias;
    }
}

// =====================================================================
extern "C" void kernel_launch(void* const* d_in, const int* in_sizes, int n_in,
                              void* d_out, int out_size, void* d_ws, size_t ws_size,
                              hipStream_t stream){
    (void)in_sizes; (void)n_in; (void)out_size; (void)ws_size;
    const float* x   = (const float*)d_in[0];
    const float* w1  = (const float*)d_in[1];
    const float* w2  = (const float*)d_in[2];
    const float* w3  = (const float*)d_in[3];
    const float* w4  = (const float*)d_in[4];
    const float* w5  = (const float*)d_in[5];
    const float* lw1 = (const float*)d_in[6];
    const float* lw2 = (const float*)d_in[7];
    const float* lb2 = (const float*)d_in[8];
    const float* lw3 = (const float*)d_in[9];
    const float* lb3 = (const float*)d_in[10];
    const float* g1 = (const float*)d_in[11]; const float* b1 = (const float*)d_in[12];
    const float* g2 = (const float*)d_in[13]; const float* b2 = (const float*)d_in[14];
    const float* g3 = (const float*)d_in[15]; const float* b3 = (const float*)d_in[16];
    const float* g4 = (const float*)d_in[17]; const float* b4 = (const float*)d_in[18];
    const float* g5 = (const float*)d_in[19]; const float* b5 = (const float*)d_in[20];
    const float* g6 = (const float*)d_in[21]; const float* b6 = (const float*)d_in[22];
    const float* g7 = (const float*)d_in[23]; const float* b7 = (const float*)d_in[24];

    char* base = (char*)d_ws;
    size_t off = 0;
    auto alloc = [&](size_t bytes) -> char* {
        char* pp = base + off;
        off += (bytes + 255) & ~(size_t)255;
        return pp;
    };
    float*  XT   = (float*) alloc(sizeof(float) * (size_t)cB * cN * 128);
    float*  CAT  = (float*) alloc(sizeof(float) * (size_t)cB * 512 * cN);
    float*  Z    = (float*) alloc(sizeof(float) * (size_t)cB * 1024 * cN);
    float*  MB   = (float*) alloc(sizeof(float) * (size_t)cB * cN * 256);
    int*    IDX  = (int*)   alloc(sizeof(int)   * (size_t)cB * cN * cKnn);
    float*  XX   = (float*) alloc(sizeof(float) * (size_t)cB * cN);
    float*  BSUM = (float*) alloc(sizeof(float) * 64 * 256);
    float*  BSQ  = (float*) alloc(sizeof(float) * 64 * 256);
    float2* STATS= (float2*)alloc(sizeof(float2) * 1024);
    float*  WT1  = (float*) alloc(sizeof(float) * 128 * 256);
    float*  WTD  = (float*) alloc(sizeof(float) * 128 * 256);
    float*  P    = (float*) alloc(sizeof(float) * (size_t)cB * 2048);
    float*  H1   = (float*) alloc(sizeof(float) * (size_t)cB * 512);
    float*  H2   = (float*) alloc(sizeof(float) * (size_t)cB * 256);

    const float invcnt = 1.f / (float)(cB * cN * cKnn);
    dim3 knnGrid(cN / 32, cB);
    dim3 convGrid(cN / 4, cB);

    // ---- layer 1 (Cin=3, O=64) ----
    k_transpose3<<<64, 256, 0, stream>>>(x, XT);
    k_xx<3><<<64, 256, 0, stream>>>(XT, XX);
    k_knn<3><<<knnGrid, 256, 0, stream>>>(XT, XX, IDX);
    k_prepw<3, 64><<<1, 256, 0, stream>>>(w1, WT1, WTD);
    hipMemsetAsync(BSUM, 0, sizeof(float) * 2 * 64 * 256, stream);
    k_conv<3, 64><<<convGrid, 256, 0, stream>>>(XT, IDX, WT1, WTD, MB, BSUM, BSQ);
    k_redstats<64><<<1, 256, 0, stream>>>(BSUM, BSQ, g1, b1, STATS, invcnt);
    k_norm<64, true><<<(cB * cN * 64) / 256, 256, 0, stream>>>(MB, STATS, CAT, XT, 0);

    // ---- layer 2 (Cin=64, O=64) ----
    k_xx<64><<<64, 256, 0, stream>>>(XT, XX);
    k_knn<64><<<knnGrid, 256, 0, stream>>>(XT, XX, IDX);
    k_prepw<64, 64><<<16, 256, 0, stream>>>(w2, WT1, WTD);
    hipMemsetAsync(BSUM, 0, sizeof(float) * 2 * 64 * 256, stream);
    k_conv<64, 64><<<convGrid, 256, 0, stream>>>(XT, IDX, WT1, WTD, MB, BSUM, BSQ);
    k_redstats<64><<<1, 256, 0, stream>>>(BSUM, BSQ, g2, b2, STATS, invcnt);
    k_norm<64, true><<<(cB * cN * 64) / 256, 256, 0, stream>>>(MB, STATS, CAT, XT, 64);

    // ---- layer 3 (Cin=64, O=128) ----
    k_xx<64><<<64, 256, 0, stream>>>(XT, XX);
    k_knn<64><<<knnGrid, 256, 0, stream>>>(XT, XX, IDX);
    k_prepw<64, 128><<<32, 256, 0, stream>>>(w3, WT1, WTD);
    hipMemsetAsync(BSUM, 0, sizeof(float) * 2 * 64 * 256, stream);
    k_conv<64, 128><<<convGrid, 256, 0, stream>>>(XT, IDX, WT1, WTD, MB, BSUM, BSQ);
    k_redstats<128><<<1, 256, 0, stream>>>(BSUM, BSQ, g3, b3, STATS, invcnt);
    k_norm<128, true><<<(cB * cN * 128) / 256, 256, 0, stream>>>(MB, STATS, CAT, XT, 128);

    // ---- layer 4 (Cin=128, O=256) ----
    k_xx<128><<<64, 256, 0, stream>>>(XT, XX);
    k_knn<128><<<knnGrid, 256, 0, stream>>>(XT, XX, IDX);
    k_prepw<128, 256><<<128, 256, 0, stream>>>(w4, WT1, WTD);
    hipMemsetAsync(BSUM, 0, sizeof(float) * 2 * 64 * 256, stream);
    k_conv<128, 256><<<convGrid, 256, 0, stream>>>(XT, IDX, WT1, WTD, MB, BSUM, BSQ);
    k_redstats<256><<<1, 256, 0, stream>>>(BSUM, BSQ, g4, b4, STATS, invcnt);
    k_norm<256, false><<<(cB * cN * 256) / 256, 256, 0, stream>>>(MB, STATS, CAT, nullptr, 256);

    // ---- head ----
    k_gemm_z<<<dim3(cN / 64, 1024 / 64, cB), 256, 0, stream>>>(w5, CAT, Z);
    k_zstats<<<1024, 256, 0, stream>>>(Z, g5, b5, STATS);
    k_pool<<<dim3(1024, cB), 256, 0, stream>>>(Z, STATS, P);
    k_fc1<<<512, 64, 0, stream>>>(P, lw1, g6, b6, H1);
    k_fc2<<<256, 64, 0, stream>>>(H1, lw2, lb2, g7, b7, H2);
    k_fc3<<<40, 64, 0, stream>>>(H2, lw3, lb3, (float*)d_out);
}

// Round 3
// 1805.235 us; speedup vs baseline: 2.5261x; 2.5261x over previous
//
#include <hip/hip_runtime.h>
#include <float.h>

constexpr int cB = 8;
constexpr int cN = 2048;
constexpr int cKnn = 20;
constexpr float F_EPS = 1e-5f;
constexpr float F_SLOPE = 0.2f;

__device__ __forceinline__ float lrelu(float x){ return x >= 0.f ? x : F_SLOPE * x; }

// ---------------- transpose x (B,3,N) -> xt (B,N,4) zero-padded ----------------
__global__ void k_transpose3(const float* __restrict__ x, float* __restrict__ xt){
    int i = blockIdx.x * 256 + threadIdx.x;
    if(i >= cB * cN) return;
    int b = i / cN, n = i % cN;
    const float* xb = x + (size_t)b * 3 * cN;
    float* o = xt + (size_t)i * 4;
    o[0] = xb[n]; o[1] = xb[cN + n]; o[2] = xb[2*cN + n]; o[3] = 0.f;
}

// ---------------- xx[b][n] = sum_c xt[b][n][c]^2 (stride C, C%4==0) ----------------
template<int C>
__global__ void k_xx(const float* __restrict__ xt, float* __restrict__ xx){
    int i = blockIdx.x * 256 + threadIdx.x;
    if(i >= cB * cN) return;
    const float* r = xt + (size_t)i * C;
    const float4* r4 = (const float4*)r;
    float s = 0.f;
    #pragma unroll
    for(int c = 0; c < C/4; c++){
        float4 v = r4[c];
        s += v.x*v.x + v.y*v.y + v.z*v.z + v.w*v.w;
    }
    xx[i] = s;
}

// ---------------- score GEMM: S[z][q][j] = 2*dot(x_q,x_j) - xx[j] ----------------
// grid (cN/64 j-tiles, cN/64 q-tiles, 4 batches), block 256. S holds 4 batches.
template<int C>
__global__ __launch_bounds__(256) void k_score(const float* __restrict__ xt, const float* __restrict__ xx,
                                               float* __restrict__ S, int b_base){
    constexpr int CT = (C >= 16) ? 16 : C;
    __shared__ float at[16][68];
    __shared__ float bt[16][68];
    int tid = threadIdx.x;
    int j0 = blockIdx.x * 64, q0 = blockIdx.y * 64, z = blockIdx.z;
    int b = b_base + z;
    const float* Xb = xt + (size_t)b * cN * C;
    int no = tid % 16, mo = tid / 16;
    float acc[4][4] = {};
    for(int c0 = 0; c0 < C; c0 += CT){
        if constexpr (CT == 16){
            int row = tid >> 2, c4 = tid & 3;
            float4 v = *(const float4*)(Xb + (size_t)(q0 + row) * C + c0 + c4 * 4);
            at[c4*4+0][row] = v.x; at[c4*4+1][row] = v.y;
            at[c4*4+2][row] = v.z; at[c4*4+3][row] = v.w;
            float4 w = *(const float4*)(Xb + (size_t)(j0 + row) * C + c0 + c4 * 4);
            bt[c4*4+0][row] = w.x; bt[c4*4+1][row] = w.y;
            bt[c4*4+2][row] = w.z; bt[c4*4+3][row] = w.w;
        } else {
            if(tid < 64){
                float4 v = *(const float4*)(Xb + (size_t)(q0 + tid) * C);
                at[0][tid] = v.x; at[1][tid] = v.y; at[2][tid] = v.z; at[3][tid] = v.w;
                float4 w = *(const float4*)(Xb + (size_t)(j0 + tid) * C);
                bt[0][tid] = w.x; bt[1][tid] = w.y; bt[2][tid] = w.z; bt[3][tid] = w.w;
            }
        }
        __syncthreads();
        #pragma unroll
        for(int c = 0; c < CT; c++){
            float av[4] = { at[c][mo*4+0], at[c][mo*4+1], at[c][mo*4+2], at[c][mo*4+3] };
            float bv[4] = { bt[c][no*4+0], bt[c][no*4+1], bt[c][no*4+2], bt[c][no*4+3] };
            #pragma unroll
            for(int i2 = 0; i2 < 4; i2++)
                #pragma unroll
                for(int j2 = 0; j2 < 4; j2++)
                    acc[i2][j2] += av[i2] * bv[j2];
        }
        __syncthreads();
    }
    const float* xxb = xx + (size_t)b * cN;
    float4 xv = *(const float4*)(xxb + j0 + no * 4);
    #pragma unroll
    for(int i2 = 0; i2 < 4; i2++){
        float4 o = make_float4(2.f*acc[i2][0] - xv.x, 2.f*acc[i2][1] - xv.y,
                               2.f*acc[i2][2] - xv.z, 2.f*acc[i2][3] - xv.w);
        *(float4*)(S + ((size_t)z * cN + q0 + mo * 4 + i2) * cN + j0 + no * 4) = o;
    }
}

// ---------------- select top-20 per row, branch-free binary search on key bits ----------------
// one wave per query; lane l holds scores j = i*64+l, i=0..31.
__global__ __launch_bounds__(256) void k_select(const float* __restrict__ S, int* __restrict__ idxout,
                                                int b_base){
    int wid = threadIdx.x >> 6, lane = threadIdx.x & 63;
    int n = blockIdx.x * 4 + wid;
    int z = blockIdx.y;
    const float* row = S + ((size_t)z * cN + n) * cN;
    unsigned key[32];
    #pragma unroll
    for(int i = 0; i < 32; i++){
        float s = row[i * 64 + lane];
        unsigned u = __float_as_uint(s);
        key[i] = (s >= 0.f) ? (u | 0x80000000u) : ~u;
    }
    // T = key of 20th-largest (max T with count(key>=T) >= 20)
    unsigned T = 0;
    for(int bit = 31; bit >= 0; bit--){
        unsigned test = T | (1u << bit);
        int c = 0;
        #pragma unroll
        for(int i = 0; i < 32; i++) c += (key[i] >= test) ? 1 : 0;
        #pragma unroll
        for(int off = 32; off; off >>= 1) c += __shfl_xor(c, off);
        if(c >= cKnn) T = test;
    }
    int nab = 0;
    #pragma unroll
    for(int i = 0; i < 32; i++) nab += (key[i] > T) ? 1 : 0;
    #pragma unroll
    for(int off = 32; off; off >>= 1) nab += __shfl_xor(nab, off);
    int need = cKnn - nab;

    int* out = idxout + ((size_t)(b_base + z) * cN + n) * cKnn;
    int pos = 0;
    #pragma unroll
    for(int i = 0; i < 32; i++){
        bool hi = key[i] > T;
        unsigned long long m = __ballot(hi);
        if(hi){
            int r = __popcll(m & ((1ull << lane) - 1ull));
            out[pos + r] = i * 64 + lane;
        }
        pos += __popcll(m);
    }
    // ties at T: fill remaining `need` in ascending j order (matches top_k low-index ties)
    #pragma unroll
    for(int i = 0; i < 32; i++){
        bool eq = (key[i] == T);
        unsigned long long m = __ballot(eq);
        int r = __popcll(m & ((1ull << lane) - 1ull));
        if(eq && r < need) out[pos + r] = i * 64 + lane;
        int t = __popcll(m); t = t < need ? t : need; t = t > 0 ? t : 0;
        pos += t; need -= t;
    }
}

// ---------------- weight prep: wt1[c][o]=w[o][c] (on nbr-ctr), wtd[c][o]=w[o][Cin+c] (on ctr) ----
template<int Cin, int O>
__global__ void k_prepw(const float* __restrict__ w, float* __restrict__ wt1, float* __restrict__ wtd){
    int e = blockIdx.x * 256 + threadIdx.x;
    if(e >= Cin * O) return;
    int o = e % O, c = e / O;
    wt1[c * O + o] = w[o * 2 * Cin + c];
    wtd[c * O + o] = w[o * 2 * Cin + Cin + c];
}

// ---------------- edge conv + max_k + stats (CSTR = row stride of xt) ----------------
template<int Cin, int O, int CSTR = Cin>
__global__ __launch_bounds__(256) void k_conv(const float* __restrict__ xt, const int* __restrict__ idx,
                                              const float* __restrict__ wt1, const float* __restrict__ wtd,
                                              float* __restrict__ Mbuf, float* __restrict__ bsum, float* __restrict__ bsq){
    constexpr int P = 4;
    constexpr int GR = 256 / O;
    constexpr int PSER = P / GR;
    __shared__ float ctr[P][Cin];
    __shared__ __align__(16) float df[P][Cin][cKnn];

    int tid = threadIdx.x;
    int b = blockIdx.y;
    int n0 = blockIdx.x * P;
    const float* xb = xt + (size_t)b * cN * CSTR;

    for(int e = tid; e < P * Cin; e += 256){
        int p = e / Cin, c = e % Cin;
        ctr[p][c] = xb[(size_t)(n0 + p) * CSTR + c];
    }
    __syncthreads();

    if constexpr (Cin % 4 == 0){
        constexpr int C4 = Cin / 4;
        for(int e = tid; e < P * cKnn * C4; e += 256){
            int p = e / (cKnn * C4); int rem = e % (cKnn * C4);
            int k = rem / C4; int c4 = rem % C4;
            int j = idx[((size_t)b * cN + n0 + p) * cKnn + k];
            float4 v = *(const float4*)(xb + (size_t)j * CSTR + c4 * 4);
            int c = c4 * 4;
            df[p][c  ][k] = v.x - ctr[p][c  ];
            df[p][c+1][k] = v.y - ctr[p][c+1];
            df[p][c+2][k] = v.z - ctr[p][c+2];
            df[p][c+3][k] = v.w - ctr[p][c+3];
        }
    } else {
        for(int e = tid; e < P * cKnn * Cin; e += 256){
            int p = e / (cKnn * Cin); int rem = e % (cKnn * Cin);
            int k = rem / Cin; int c = rem % Cin;
            int j = idx[((size_t)b * cN + n0 + p) * cKnn + k];
            df[p][c][k] = xb[(size_t)j * CSTR + c] - ctr[p][c];
        }
    }
    __syncthreads();

    int o = tid % O;
    int grp = tid / O;
    float lsum = 0.f, lsq = 0.f;

    for(int s = 0; s < PSER; s++){
        int p = grp * PSER + s;
        float t = 0.f;
        for(int c = 0; c < Cin; c++) t += wtd[c * O + o] * ctr[p][c];
        float acc[cKnn];
        #pragma unroll
        for(int k = 0; k < cKnn; k++) acc[k] = t;
        for(int c = 0; c < Cin; c++){
            float wv = wt1[c * O + o];
            const float4* dr = (const float4*)&df[p][c][0];
            #pragma unroll
            for(int k4 = 0; k4 < cKnn / 4; k4++){
                float4 d4 = dr[k4];
                acc[k4*4+0] += wv * d4.x;
                acc[k4*4+1] += wv * d4.y;
                acc[k4*4+2] += wv * d4.z;
                acc[k4*4+3] += wv * d4.w;
            }
        }
        float mx = -FLT_MAX;
        #pragma unroll
        for(int k = 0; k < cKnn; k++){
            float y = acc[k];
            mx = fmaxf(mx, y);
            lsum += y; lsq += y * y;
        }
        Mbuf[((size_t)b * cN + n0 + p) * O + o] = mx;
    }
    int bkt = blockIdx.x & 63;
    atomicAdd(&bsum[bkt * O + o], lsum);
    atomicAdd(&bsq [bkt * O + o], lsq);
}

// ---------------- reduce buckets -> scale/shift ----------------
template<int O>
__global__ void k_redstats(const float* __restrict__ bsum, const float* __restrict__ bsq,
                           const float* __restrict__ g, const float* __restrict__ bb,
                           float2* __restrict__ stats, float invcnt){
    int o = threadIdx.x;
    if(o >= O) return;
    float s = 0.f, q = 0.f;
    for(int k = 0; k < 64; k++){ s += bsum[k * O + o]; q += bsq[k * O + o]; }
    float m = s * invcnt;
    float v = q * invcnt - m * m;
    float sc = g[o] * rsqrtf(v + F_EPS);
    stats[o] = make_float2(sc, bb[o] - m * sc);
}

// ---------------- normalize max-pooled values, write cat (+ xt for next layer) ----------------
template<int O, bool WXT>
__global__ void k_norm(const float* __restrict__ Mbuf, const float2* __restrict__ stats,
                       float* __restrict__ cat, float* __restrict__ xtn, int ooff){
    size_t i = (size_t)blockIdx.x * 256 + threadIdx.x;
    if(i >= (size_t)cB * cN * O) return;
    int o = i % O;
    size_t bn = i / O;
    int n = bn % cN; int b = bn / cN;
    float2 st = stats[o];
    float y = lrelu(Mbuf[i] * st.x + st.y);
    cat[((size_t)b * 512 + ooff + o) * cN + n] = y;
    if(WXT) xtn[i] = y;
}

// ---------------- z = w5 (1024,512) @ cat (B,512,N) -> (B,1024,N) ----------------
__global__ __launch_bounds__(256) void k_gemm_z(const float* __restrict__ w5, const float* __restrict__ cat,
                                                float* __restrict__ z){
    constexpr int CT = 16;
    __shared__ float at[CT][68];
    __shared__ float bt[CT][68];
    int tid = threadIdx.x;
    int n0 = blockIdx.x * 64, o0 = blockIdx.y * 64, b = blockIdx.z;
    int no = tid % 16, mo = tid / 16;
    float acc[4][4] = {};
    for(int c0 = 0; c0 < 512; c0 += CT){
        {
            int row = tid >> 2, c4 = tid & 3;
            float4 v = *(const float4*)(w5 + (size_t)(o0 + row) * 512 + c0 + c4 * 4);
            at[c4*4+0][row] = v.x; at[c4*4+1][row] = v.y;
            at[c4*4+2][row] = v.z; at[c4*4+3][row] = v.w;
        }
        {
            int cc = tid >> 4, n4 = tid & 15;
            float4 v = *(const float4*)(cat + ((size_t)b * 512 + c0 + cc) * cN + n0 + n4 * 4);
            bt[cc][n4*4+0] = v.x; bt[cc][n4*4+1] = v.y; bt[cc][n4*4+2] = v.z; bt[cc][n4*4+3] = v.w;
        }
        __syncthreads();
        #pragma unroll
        for(int c = 0; c < CT; c++){
            float av[4] = { at[c][mo*4+0], at[c][mo*4+1], at[c][mo*4+2], at[c][mo*4+3] };
            float bv[4] = { bt[c][no*4+0], bt[c][no*4+1], bt[c][no*4+2], bt[c][no*4+3] };
            #pragma unroll
            for(int i2 = 0; i2 < 4; i2++)
                #pragma unroll
                for(int j2 = 0; j2 < 4; j2++)
                    acc[i2][j2] += av[i2] * bv[j2];
        }
        __syncthreads();
    }
    #pragma unroll
    for(int i2 = 0; i2 < 4; i2++){
        float4 v = make_float4(acc[i2][0], acc[i2][1], acc[i2][2], acc[i2][3]);
        *(float4*)(z + ((size_t)b * 1024 + o0 + mo * 4 + i2) * cN + n0 + no * 4) = v;
    }
}

// ---------------- z stats per channel (over B,N) -> scale/shift ----------------
__global__ void k_zstats(const float* __restrict__ z, const float* __restrict__ g5,
                         const float* __restrict__ b5, float2* __restrict__ stats){
    int o = blockIdx.x;
    int tid = threadIdx.x;
    __shared__ float ss[256], sq[256];
    float s = 0.f, q = 0.f;
    for(int e = tid; e < cB * cN; e += 256){
        int b = e >> 11, n = e & 2047;
        float v = z[((size_t)b * 1024 + o) * cN + n];
        s += v; q += v * v;
    }
    ss[tid] = s; sq[tid] = q; __syncthreads();
    for(int st = 128; st; st >>= 1){
        if(tid < st){ ss[tid] += ss[tid + st]; sq[tid] += sq[tid + st]; }
        __syncthreads();
    }
    if(tid == 0){
        float m = ss[0] / (float)(cB * cN);
        float v = sq[0] / (float)(cB * cN) - m * m;
        float sc = g5[o] * rsqrtf(v + F_EPS);
        stats[o] = make_float2(sc, b5[o] - m * sc);
    }
}

// ---------------- pooling ----------------
__global__ void k_pool(const float* __restrict__ z, const float2* __restrict__ stats,
                       float* __restrict__ p){
    int o = blockIdx.x, b = blockIdx.y;
    int tid = threadIdx.x;
    float2 st = stats[o];
    const float* row = z + ((size_t)b * 1024 + o) * cN;
    float mx = -FLT_MAX, sm = 0.f;
    for(int n = tid; n < cN; n += 256){
        float y = lrelu(row[n] * st.x + st.y);
        mx = fmaxf(mx, y); sm += y;
    }
    __shared__ float smx[256], ssm[256];
    smx[tid] = mx; ssm[tid] = sm; __syncthreads();
    for(int st2 = 128; st2; st2 >>= 1){
        if(tid < st2){ smx[tid] = fmaxf(smx[tid], smx[tid + st2]); ssm[tid] += ssm[tid + st2]; }
        __syncthreads();
    }
    if(tid == 0){
        p[(size_t)b * 2048 + o] = smx[0];
        p[(size_t)b * 2048 + 1024 + o] = ssm[0] * (1.f / cN);
    }
}

// ---------------- FC layers with batch-axis BN ----------------
__global__ void k_fc1(const float* __restrict__ p, const float* __restrict__ lw1,
                      const float* __restrict__ g6, const float* __restrict__ b6,
                      float* __restrict__ h1){
    int f = blockIdx.x;
    int tid = threadIdx.x;
    const float* wrow = lw1 + (size_t)f * 2048;
    float acc[cB] = {};
    for(int i = tid; i < 2048; i += 64){
        float wv = wrow[i];
        #pragma unroll
        for(int b = 0; b < cB; b++) acc[b] += p[(size_t)b * 2048 + i] * wv;
    }
    #pragma unroll
    for(int b = 0; b < cB; b++){
        float v = acc[b];
        for(int off = 32; off; off >>= 1) v += __shfl_down(v, off);
        acc[b] = v;
    }
    if(tid == 0){
        float m = 0.f;
        #pragma unroll
        for(int b = 0; b < cB; b++) m += acc[b];
        m *= (1.f / cB);
        float var = 0.f;
        #pragma unroll
        for(int b = 0; b < cB; b++){ float d = acc[b] - m; var += d * d; }
        var *= (1.f / cB);
        float sc = g6[f] * rsqrtf(var + F_EPS);
        float sh = b6[f] - m * sc;
        #pragma unroll
        for(int b = 0; b < cB; b++) h1[(size_t)b * 512 + f] = lrelu(acc[b] * sc + sh);
    }
}

__global__ void k_fc2(const float* __restrict__ h1, const float* __restrict__ lw2,
                      const float* __restrict__ lb2, const float* __restrict__ g7,
                      const float* __restrict__ b7, float* __restrict__ h2){
    int f = blockIdx.x;
    int tid = threadIdx.x;
    const float* wrow = lw2 + (size_t)f * 512;
    float acc[cB] = {};
    for(int i = tid; i < 512; i += 64){
        float wv = wrow[i];
        #pragma unroll
        for(int b = 0; b < cB; b++) acc[b] += h1[(size_t)b * 512 + i] * wv;
    }
    #pragma unroll
    for(int b = 0; b < cB; b++){
        float v = acc[b];
        for(int off = 32; off; off >>= 1) v += __shfl_down(v, off);
        acc[b] = v;
    }
    if(tid == 0){
        float bias = lb2[f];
        #pragma unroll
        for(int b = 0; b < cB; b++) acc[b] += bias;
        float m = 0.f;
        #pragma unroll
        for(int b = 0; b < cB; b++) m += acc[b];
        m *= (1.f / cB);
        float var = 0.f;
        #pragma unroll
        for(int b = 0; b < cB; b++){ float d = acc[b] - m; var += d * d; }
        var *= (1.f / cB);
        float sc = g7[f] * rsqrtf(var + F_EPS);
        float sh = b7[f] - m * sc;
        #pragma unroll
        for(int b = 0; b < cB; b++) h2[(size_t)b * 256 + f] = lrelu(acc[b] * sc + sh);
    }
}

__global__ void k_fc3(const float* __restrict__ h2, const float* __restrict__ lw3,
                      const float* __restrict__ lb3, float* __restrict__ out){
    int cls = blockIdx.x;
    int tid = threadIdx.x;
    const float* wrow = lw3 + (size_t)cls * 256;
    float acc[cB] = {};
    for(int i = tid; i < 256; i += 64){
        float wv = wrow[i];
        #pragma unroll
        for(int b = 0; b < cB; b++) acc[b] += h2[(size_t)b * 256 + i] * wv;
    }
    #pragma unroll
    for(int b = 0; b < cB; b++){
        float v = acc[b];
        for(int off = 32; off; off >>= 1) v += __shfl_down(v, off);
        acc[b] = v;
    }
    if(tid == 0){
        float bias = lb3[cls];
        #pragma unroll
        for(int b = 0; b < cB; b++) out[(size_t)b * 40 + cls] = acc[b] + bias;
    }
}

// =====================================================================
extern "C" void kernel_launch(void* const* d_in, const int* in_sizes, int n_in,
                              void* d_out, int out_size, void* d_ws, size_t ws_size,
                              hipStream_t stream){
    (void)in_sizes; (void)n_in; (void)out_size; (void)ws_size;
    const float* x   = (const float*)d_in[0];
    const float* w1  = (const float*)d_in[1];
    const float* w2  = (const float*)d_in[2];
    const float* w3  = (const float*)d_in[3];
    const float* w4  = (const float*)d_in[4];
    const float* w5  = (const float*)d_in[5];
    const float* lw1 = (const float*)d_in[6];
    const float* lw2 = (const float*)d_in[7];
    const float* lb2 = (const float*)d_in[8];
    const float* lw3 = (const float*)d_in[9];
    const float* lb3 = (const float*)d_in[10];
    const float* g1 = (const float*)d_in[11]; const float* b1 = (const float*)d_in[12];
    const float* g2 = (const float*)d_in[13]; const float* b2 = (const float*)d_in[14];
    const float* g3 = (const float*)d_in[15]; const float* b3 = (const float*)d_in[16];
    const float* g4 = (const float*)d_in[17]; const float* b4 = (const float*)d_in[18];
    const float* g5 = (const float*)d_in[19]; const float* b5 = (const float*)d_in[20];
    const float* g6 = (const float*)d_in[21]; const float* b6 = (const float*)d_in[22];
    const float* g7 = (const float*)d_in[23]; const float* b7 = (const float*)d_in[24];

    char* base = (char*)d_ws;
    size_t off = 0;
    auto alloc = [&](size_t bytes) -> char* {
        char* pp = base + off;
        off += (bytes + 255) & ~(size_t)255;
        return pp;
    };
    float*  XT   = (float*) alloc(sizeof(float) * (size_t)cB * cN * 128);
    float*  CAT  = (float*) alloc(sizeof(float) * (size_t)cB * 512 * cN);
    float*  Z    = (float*) alloc(sizeof(float) * (size_t)cB * 1024 * cN);  // also reused as score buf (4 batches)
    float*  MB   = (float*) alloc(sizeof(float) * (size_t)cB * cN * 256);
    int*    IDX  = (int*)   alloc(sizeof(int)   * (size_t)cB * cN * cKnn);
    float*  XX   = (float*) alloc(sizeof(float) * (size_t)cB * cN);
    float*  BSUM = (float*) alloc(sizeof(float) * 64 * 256);
    float*  BSQ  = (float*) alloc(sizeof(float) * 64 * 256);
    float2* STATS= (float2*)alloc(sizeof(float2) * 1024);
    float*  WT1  = (float*) alloc(sizeof(float) * 128 * 256);
    float*  WTD  = (float*) alloc(sizeof(float) * 128 * 256);
    float*  P    = (float*) alloc(sizeof(float) * (size_t)cB * 2048);
    float*  H1   = (float*) alloc(sizeof(float) * (size_t)cB * 512);
    float*  H2   = (float*) alloc(sizeof(float) * (size_t)cB * 256);
    float*  SC   = Z;  // 64 MB: scores for 4 batches per half

    const float invcnt = 1.f / (float)(cB * cN * cKnn);
    dim3 convGrid(cN / 4, cB);
    dim3 scGrid(cN / 64, cN / 64, 4);
    dim3 selGrid(cN / 4, 4);

    // ---- layer 1 (Cin=3 padded to 4, O=64) ----
    k_transpose3<<<64, 256, 0, stream>>>(x, XT);
    k_xx<4><<<64, 256, 0, stream>>>(XT, XX);
    for(int h = 0; h < 2; h++){
        k_score<4><<<scGrid, 256, 0, stream>>>(XT, XX, SC, 4 * h);
        k_select<<<selGrid, 256, 0, stream>>>(SC, IDX, 4 * h);
    }
    k_prepw<3, 64><<<1, 256, 0, stream>>>(w1, WT1, WTD);
    hipMemsetAsync(BSUM, 0, sizeof(float) * 2 * 64 * 256, stream);
    k_conv<3, 64, 4><<<convGrid, 256, 0, stream>>>(XT, IDX, WT1, WTD, MB, BSUM, BSQ);
    k_redstats<64><<<1, 256, 0, stream>>>(BSUM, BSQ, g1, b1, STATS, invcnt);
    k_norm<64, true><<<(cB * cN * 64) / 256, 256, 0, stream>>>(MB, STATS, CAT, XT, 0);

    // ---- layer 2 (Cin=64, O=64) ----
    k_xx<64><<<64, 256, 0, stream>>>(XT, XX);
    for(int h = 0; h < 2; h++){
        k_score<64><<<scGrid, 256, 0, stream>>>(XT, XX, SC, 4 * h);
        k_select<<<selGrid, 256, 0, stream>>>(SC, IDX, 4 * h);
    }
    k_prepw<64, 64><<<16, 256, 0, stream>>>(w2, WT1, WTD);
    hipMemsetAsync(BSUM, 0, sizeof(float) * 2 * 64 * 256, stream);
    k_conv<64, 64><<<convGrid, 256, 0, stream>>>(XT, IDX, WT1, WTD, MB, BSUM, BSQ);
    k_redstats<64><<<1, 256, 0, stream>>>(BSUM, BSQ, g2, b2, STATS, invcnt);
    k_norm<64, true><<<(cB * cN * 64) / 256, 256, 0, stream>>>(MB, STATS, CAT, XT, 64);

    // ---- layer 3 (Cin=64, O=128) ----
    k_xx<64><<<64, 256, 0, stream>>>(XT, XX);
    for(int h = 0; h < 2; h++){
        k_score<64><<<scGrid, 256, 0, stream>>>(XT, XX, SC, 4 * h);
        k_select<<<selGrid, 256, 0, stream>>>(SC, IDX, 4 * h);
    }
    k_prepw<64, 128><<<32, 256, 0, stream>>>(w3, WT1, WTD);
    hipMemsetAsync(BSUM, 0, sizeof(float) * 2 * 64 * 256, stream);
    k_conv<64, 128><<<convGrid, 256, 0, stream>>>(XT, IDX, WT1, WTD, MB, BSUM, BSQ);
    k_redstats<128><<<1, 256, 0, stream>>>(BSUM, BSQ, g3, b3, STATS, invcnt);
    k_norm<128, true><<<(cB * cN * 128) / 256, 256, 0, stream>>>(MB, STATS, CAT, XT, 128);

    // ---- layer 4 (Cin=128, O=256) ----
    k_xx<128><<<64, 256, 0, stream>>>(XT, XX);
    for(int h = 0; h < 2; h++){
        k_score<128><<<scGrid, 256, 0, stream>>>(XT, XX, SC, 4 * h);
        k_select<<<selGrid, 256, 0, stream>>>(SC, IDX, 4 * h);
    }
    k_prepw<128, 256><<<128, 256, 0, stream>>>(w4, WT1, WTD);
    hipMemsetAsync(BSUM, 0, sizeof(float) * 2 * 64 * 256, stream);
    k_conv<128, 256><<<convGrid, 256, 0, stream>>>(XT, IDX, WT1, WTD, MB, BSUM, BSQ);
    k_redstats<256><<<1, 256, 0, stream>>>(BSUM, BSQ, g4, b4, STATS, invcnt);
    k_norm<256, false><<<(cB * cN * 256) / 256, 256, 0, stream>>>(MB, STATS, CAT, nullptr, 256);

    // ---- head ----
    k_gemm_z<<<dim3(cN / 64, 1024 / 64, cB), 256, 0, stream>>>(w5, CAT, Z);
    k_zstats<<<1024, 256, 0, stream>>>(Z, g5, b5, STATS);
    k_pool<<<dim3(1024, cB), 256, 0, stream>>>(Z, STATS, P);
    k_fc1<<<512, 64, 0, stream>>>(P, lw1, g6, b6, H1);
    k_fc2<<<256, 64, 0, stream>>>(H1, lw2, lb2, g7, b7, H2);
    k_fc3<<<40, 64, 0, stream>>>(H2, lw3, lb3, (float*)d_out);
}